// Round 11
// baseline (191.256 us; speedup 1.0000x reference)
//
#include <hip/hip_runtime.h>

#define D 128
#define NB 64               // histogram/scatter slices
#define HWORDS 12544        // full-N byte-packed hist words (50176 B LDS, single pass)
#define HRANGE (HWORDS * 4)
#define RBITS 14            // scatter z-split: 16384 bins per range
#define RSIZE (1 << RBITS)
#define RWORDS8 (RSIZE / 4) // 4096 byte-packed words = 16 KB LDS
#define WT_STRIDE 136

typedef short short8 __attribute__((ext_vector_type(8)));
typedef float f32x4 __attribute__((ext_vector_type(4)));
typedef float f32x2 __attribute__((ext_vector_type(2)));

static __device__ __forceinline__ unsigned short f2bf(float f) {
    unsigned int u = __float_as_uint(f);
    unsigned int r = (u + 0x7FFFu + ((u >> 16) & 1u)) >> 16;
    return (unsigned short)r;
}
static __device__ __forceinline__ unsigned int pk2bf(float lo, float hi) {
    return (unsigned int)f2bf(lo) | ((unsigned int)f2bf(hi) << 16);
}

// Counts byte-packed (4 nodes/word): per-slice count and cumulative per-node
// prefix are both bounded by total degree ~ Poisson(16) tail < 64 << 255.

// ---------------- K1 merged front end (one launch, 256-thread blocks):
//   zone A  [bx < 128]          : per-(type,slice) single-pass full-N byte-packed LDS
//                                 histograms (int4 edge reads); publish histdone++.
//   zone C  [128 <= bx < 257]   : weight fold + beff + zero lookback partials.
//   zone S  [257 <= bx < 257+49]: hist reduce -> norms + prefix rewrite + decoupled-
//                                 lookback scan -> offsets. t==0 spins on histdone==128
//                                 first (49 waiters out of ~6700 blocks, dispatched
//                                 AFTER their producers -> forward progress; R9's
//                                 failure was waiters >> workers, not this).
//   zone B  [rest]              : x -> bf16 + fp8 conversions (fill the device while
//                                 zone S waits/works).
// LDS = 50176 B everywhere -> 3 blocks/CU, 12 waves/CU: enough for the BW-bound
// conversions and the latency-bound hist atomics alike. ----------------
__global__ __launch_bounds__(256) void k_front(
    const int* __restrict__ src, const int* __restrict__ dst,
    unsigned int* __restrict__ hist, int E, int NW8, int nbh, int N,
    const float* __restrict__ x, unsigned short* __restrict__ xh,
    unsigned int* __restrict__ xs8, long long total4,
    const float* __restrict__ Wc, const float* __restrict__ Wa,
    const float* __restrict__ bc, const float* __restrict__ ba,
    unsigned short* __restrict__ Wt, float* __restrict__ beff,
    int* __restrict__ partial, int* __restrict__ histdone,
    float* __restrict__ norm_out, float* __restrict__ norm_in,
    int* __restrict__ offsets) {
    __shared__ __align__(16) unsigned int h[HWORDS];   // zone A hist / zone S red
    int t = threadIdx.x;
    int bx = blockIdx.x;

    if (bx < 2 * NB) {
        // ---- zone A ----
        int type = bx / NB;
        int b = bx % NB;
        const int* __restrict__ ids = type ? dst : src;
        for (int i = t; i < HWORDS; i += 256) h[i] = 0;
        __syncthreads();
        int slice = (E + NB - 1) / NB;
        int beg = b * slice;
        int end = beg + slice; if (end > E) end = E;
#define HPROC(vv) { unsigned int lv = (unsigned int)(vv); \
                    if (lv < (unsigned int)HRANGE) atomicAdd(&h[lv >> 2], 1u << ((lv & 3) * 8)); }
        int a0 = (beg + 3) & ~3; if (a0 > end) a0 = end;
        int a1 = a0 + ((end - a0) & ~3);
        for (int e = beg + t; e < a0; e += 256) HPROC(ids[e]);
        int nv = (a1 - a0) >> 2;
        const int4* idv = (const int4*)(ids + a0);
        for (int i = t; i < nv; i += 256) {
            int4 v4 = idv[i];
            HPROC(v4.x); HPROC(v4.y); HPROC(v4.z); HPROC(v4.w);
        }
        for (int e = a1 + t; e < end; e += 256) HPROC(ids[e]);
#undef HPROC
        __syncthreads();
        unsigned int* outp = hist + (size_t)bx * NW8;
        for (int i = t; i < NW8; i += 256) outp[i] = h[i];
        __syncthreads();
        if (t == 0) { __threadfence(); atomicAdd(histdone, 1); }   // publish
    } else if (bx < 2 * NB + 129) {
        // ---- zone C ----
        int cidx = bx - 2 * NB;
        if (cidx < 128) {
            int o = cidx * 256 + t;
            int k = o >> 7;
            int j = o & 127;
            float acc;
            if (k < 128) {
                acc = 0.f;
                for (int l = 0; l < 128; l++) acc += Wc[k * 128 + l] * Wa[l * 128 + j];
            } else {
                acc = Wa[k * 128 + j];
            }
            Wt[(size_t)j * 256 + k] = f2bf(acc);
        } else {
            if (t < 128) {
                float acc = ba[t];
                for (int k = 0; k < 128; k++) acc += bc[k] * Wa[k * 128 + t];
                beff[t] = acc;
            } else if (t < 192) {
                partial[t - 128] = 0;
            }
        }
    } else if (bx < 2 * NB + 129 + nbh) {
        // ---- zone S: R8/R10-verbatim hredscan body after a tiny producer wait ----
        int sb = bx - (2 * NB + 129);
        if (t == 0) {
            while (atomicAdd(histdone, 0) < 2 * NB) __builtin_amdgcn_s_sleep(16);
            __threadfence();
        }
        __syncthreads();
        int* red = (int*)h;
        int w = sb * 256 + t;
        unsigned int p[4] = {0, 0, 0, 0};
        if (w < NW8) {
            unsigned int dout[4] = {0, 0, 0, 0};
            for (int b = 0; b < NB; b++) {
                unsigned int v = hist[(size_t)b * NW8 + w];
                dout[0] += v & 0xffu;         dout[1] += (v >> 8) & 0xffu;
                dout[2] += (v >> 16) & 0xffu; dout[3] += v >> 24;
            }
            for (int b = 0; b < NB; b++) {
                unsigned int v = hist[(size_t)(NB + b) * NW8 + w];
                // thread-exclusive word: no race
                hist[(size_t)b * NW8 + w] = p[0] | (p[1] << 8) | (p[2] << 16) | (p[3] << 24);
                p[0] += v & 0xffu;         p[1] += (v >> 8) & 0xffu;
                p[2] += (v >> 16) & 0xffu; p[3] += v >> 24;
            }
            int n0 = 4 * w;
#pragma unroll
            for (int j = 0; j < 4; j++) {
                int n = n0 + j;
                if (n < N) {
                    norm_out[n] = rsqrtf((float)(dout[j] > 1 ? dout[j] : 1));
                    norm_in[n]  = rsqrtf((float)(p[j] > 1 ? p[j] : 1));
                } else {
                    p[j] = 0;
                }
            }
        }
        int s = (int)(p[0] + p[1] + p[2] + p[3]);
        red[t] = s;
        __syncthreads();
        for (int off = 1; off < 256; off <<= 1) {
            int a = (t >= off) ? red[t - off] : 0;
            __syncthreads();
            red[t] += a;
            __syncthreads();
        }
        int incl = red[t];
        if (t == 0) atomicExch(&partial[sb], red[255] + 1);  // publish (pre-zeroed)
        int pv = 0;
        if (t < sb) {                                        // lookback spin (nbh <= 64)
            int v;
            do { v = atomicAdd(&partial[t], 0); } while (v == 0);
            pv = v - 1;
        }
        __syncthreads();
        red[t] = pv;
        __syncthreads();
        for (int off = 128; off > 0; off >>= 1) {
            if (t < off) red[t] += red[t + off];
            __syncthreads();
        }
        int base = red[0];
        int excl = incl - s + base;
        int n0 = sb * 1024 + t * 4;
        if (n0 < N)     offsets[n0]     = excl;
        if (n0 + 1 < N) offsets[n0 + 1] = excl + (int)p[0];
        if (n0 + 2 < N) offsets[n0 + 2] = excl + (int)(p[0] + p[1]);
        if (n0 + 3 < N) offsets[n0 + 3] = excl + (int)(p[0] + p[1] + p[2]);
        if (sb == nbh - 1 && t == 255) offsets[N] = base + incl;
    } else {
        // ---- zone B: x -> bf16 (GEMM operand) and x -> fp8 e4m3 (gather operand).
        // fp8 quantized from UNSCALED x (R1: folding norm in doubles absmax).
        long long i = (long long)(bx - (2 * NB + 129 + nbh)) * 256 + t;
        if (i < total4) {
            float4 v = *(const float4*)&x[i * 4];
            ushort4 o;
            o.x = f2bf(v.x); o.y = f2bf(v.y); o.z = f2bf(v.z); o.w = f2bf(v.w);
            *(ushort4*)&xh[i * 4] = o;
            unsigned int p8 = __builtin_amdgcn_cvt_pk_fp8_f32(v.x, v.y, 0u, false);
            p8 = __builtin_amdgcn_cvt_pk_fp8_f32(v.z, v.w, p8, true);
            xs8[i] = p8;
        }
    }
}

// ---------------- S3: counting-sort scatter — no global atomics; XCD-grouped z;
//                  int4 dst reads (R10-verbatim) ----------------
__global__ __launch_bounds__(1024) void k_scatter(const int* __restrict__ src,
                                                  const int* __restrict__ dst,
                                                  const int* __restrict__ offsets,
                                                  const unsigned int* __restrict__ prefix,
                                                  int* __restrict__ edge_src,
                                                  int E, int NW8, int RS) {
    __shared__ unsigned int h[RWORDS8];
    int t = threadIdx.x;
    int bx = blockIdx.x;
    int low3 = bx & 7;                    // bx = (b&7) + 8*(z + RS*(b>>3))
    int rest = bx >> 3;
    int z = rest % RS;
    int b = (rest / RS) * 8 + low3;
    for (int i = t; i < RWORDS8; i += 1024) h[i] = 0;
    __syncthreads();
    int slice = (E + NB - 1) / NB;
    int beg = b * slice;
    int end = beg + slice; if (end > E) end = E;
    const unsigned int* __restrict__ prow = prefix + (size_t)b * NW8;
#define SPROC(dd, ee) { int d = (dd); \
        if ((d >> RBITS) == z) { \
            int lv = d & (RSIZE - 1); \
            int sh = (lv & 3) * 8; \
            unsigned int old = atomicAdd(&h[lv >> 2], 1u << sh); \
            int rank = (int)((old >> sh) & 0xffu); \
            int base = offsets[d] + (int)((prow[d >> 2] >> sh) & 0xffu); \
            edge_src[base + rank] = src[ee]; } }
    int a0 = (beg + 3) & ~3; if (a0 > end) a0 = end;
    int a1 = a0 + ((end - a0) & ~3);
    for (int e = beg + t; e < a0; e += 1024) SPROC(dst[e], e);
    int nv = (a1 - a0) >> 2;
    const int4* dv = (const int4*)(dst + a0);
    for (int i = t; i < nv; i += 1024) {
        int4 d4 = dv[i];
        int e = a0 + i * 4;
        SPROC(d4.x, e); SPROC(d4.y, e + 1); SPROC(d4.z, e + 2); SPROC(d4.w, e + 3);
    }
    for (int e = a1 + t; e < end; e += 1024) SPROC(dst[e], e);
#undef SPROC
}

// ---------------- S4: CSR aggregation over fp8 rows: one node per wave (R5 lesson:
//                  the gather loop is latency-bound — never serialize nodes per wave) ----------------
__global__ __launch_bounds__(256) void k_aggr(const unsigned int* __restrict__ xs8,
                                              const int* __restrict__ edge_src,
                                              const int* __restrict__ offsets,
                                              const float* __restrict__ norm_out,
                                              const float* __restrict__ norm_in,
                                              unsigned short* __restrict__ yh, int N) {
    int node = blockIdx.x * 4 + (threadIdx.x >> 6);
    int lane = threadIdx.x & 63;
    if (node >= N) return;
    int g = lane >> 5;       // group 0/1
    int li = lane & 31;      // lane-in-group: elems li*4 .. li*4+3
    int beg = offsets[node];
    int end = offsets[node + 1];
    float nd = norm_in[node];
    float acc[4] = {0.f, 0.f, 0.f, 0.f};

    for (int jb = beg; jb < end; jb += 64) {
        int cnt = end - jb; if (cnt > 64) cnt = 64;
        int eidx = 0; float nsv = 0.f;
        if (lane < cnt) {
            eidx = edge_src[jb + lane];     // one coalesced batch load
            nsv  = norm_out[eidx];          // 64 norm gathers in flight
        }
        int k = 0;
        for (; k + 16 <= cnt; k += 16) {
#pragma unroll
            for (int u = 0; u < 16; u += 2) {   // 16 rows in flight across both groups
                int kg = k + u + g;
                int s = __shfl(eidx, kg);
                float ns = __shfl(nsv, kg);
                unsigned int v = xs8[(size_t)s * 32 + li];   // 32 words per 128-elem row
                f32x2 lo = __builtin_amdgcn_cvt_pk_f32_fp8(v, false);
                f32x2 hi = __builtin_amdgcn_cvt_pk_f32_fp8(v, true);
                acc[0] += lo[0] * ns;
                acc[1] += lo[1] * ns;
                acc[2] += hi[0] * ns;
                acc[3] += hi[1] * ns;
            }
        }
        for (; k < cnt; k += 2) {
            int kg = k + g;
            if (kg < cnt) {
                int s = __shfl(eidx, kg);
                float ns = __shfl(nsv, kg);
                unsigned int v = xs8[(size_t)s * 32 + li];
                f32x2 lo = __builtin_amdgcn_cvt_pk_f32_fp8(v, false);
                f32x2 hi = __builtin_amdgcn_cvt_pk_f32_fp8(v, true);
                acc[0] += lo[0] * ns;
                acc[1] += lo[1] * ns;
                acc[2] += hi[0] * ns;
                acc[3] += hi[1] * ns;
            }
        }
    }

    // combine the 2 groups (butterfly over lane bit 5)
#pragma unroll
    for (int i = 0; i < 4; i++) acc[i] += __shfl_xor(acc[i], 32);

    if (g == 0) {
        uint2 o;
        o.x = pk2bf(acc[0] * nd, acc[1] * nd);
        o.y = pk2bf(acc[2] * nd, acc[3] * nd);
        *(uint2*)&yh[(size_t)node * D + li * 4] = o;
    }
}

// ---------------- S5: MFMA GEMM: out = [yh | xh] @ W + beff (R10-verbatim) ----------------
__global__ __launch_bounds__(256) void k_gemm(const unsigned short* __restrict__ yh,
                                              const unsigned short* __restrict__ xh,
                                              const unsigned short* __restrict__ Wt,
                                              const float* __restrict__ beff,
                                              float* __restrict__ out, int N) {
    __shared__ unsigned short Bs[128 * WT_STRIDE];

    int t = threadIdx.x;
    int w = t >> 6;
    int lane = t & 63;
    int m = lane & 15;
    int q = lane >> 4;
    int row0 = blockIdx.x * 64;
    int arow = row0 + w * 16 + m;
    bool arow_ok = arow < N;

    f32x4 acc[8];
#pragma unroll
    for (int ct = 0; ct < 8; ct++) acc[ct] = (f32x4){0.f, 0.f, 0.f, 0.f};

    for (int kh = 0; kh < 2; kh++) {
#pragma unroll
        for (int i = 0; i < 8; i++) {
            int idx = t + i * 256;
            int rr = idx >> 4;
            int cc = (idx & 15) * 8;
            *(short8*)&Bs[rr * WT_STRIDE + cc] =
                *(const short8*)&Wt[(size_t)rr * 256 + kh * 128 + cc];
        }
        __syncthreads();

        const unsigned short* Abase = (kh == 0) ? yh : xh;
        const unsigned short* arowp = Abase + (size_t)arow * D;

#pragma unroll
        for (int kk = 0; kk < 4; kk++) {
            short8 a = (short8){0,0,0,0,0,0,0,0};
            if (arow_ok) a = *(const short8*)&arowp[kk * 32 + q * 8];
#pragma unroll
            for (int ct = 0; ct < 8; ct++) {
                short8 b = *(const short8*)&Bs[(ct * 16 + m) * WT_STRIDE + kk * 32 + q * 8];
                acc[ct] = __builtin_amdgcn_mfma_f32_16x16x32_bf16(a, b, acc[ct], 0, 0, 0);
            }
        }
        __syncthreads();
    }

#pragma unroll
    for (int ct = 0; ct < 8; ct++) {
        int col = ct * 16 + m;
        float bv = beff[col];
#pragma unroll
        for (int j = 0; j < 4; j++) {
            int r = row0 + w * 16 + q * 4 + j;
            if (r < N) out[(size_t)r * D + col] = acc[ct][j] + bv;
        }
    }
}

static size_t align256(size_t v) { return (v + 255) & ~(size_t)255; }

extern "C" void kernel_launch(void* const* d_in, const int* in_sizes, int n_in,
                              void* d_out, int out_size, void* d_ws, size_t ws_size,
                              hipStream_t stream) {
    const float* x     = (const float*)d_in[0];
    const int*   src   = (const int*)d_in[1];
    const int*   dst   = (const int*)d_in[2];
    const float* Wconv = (const float*)d_in[3];
    const float* bconv = (const float*)d_in[4];
    const float* Waggr = (const float*)d_in[5];
    const float* baggr = (const float*)d_in[6];
    float* out = (float*)d_out;

    int N = in_sizes[0] / D;
    int E = in_sizes[1];
    int NW8 = (N + 3) / 4;                  // byte-packed words per histogram row
    int RS = (N + RSIZE - 1) / RSIZE;       // scatter z-splits (4 at N=50000)
    int nbh = (NW8 + 255) / 256;            // scan blocks (1024 nodes each, <= 64)
    long long total4 = (long long)N * D / 4;
    int nC4 = (int)((total4 + 255) / 256);  // conversion blocks

    char* p = (char*)d_ws;
    // hist: [src half: NB rows][dst half: NB rows]; after zone S the src half
    // holds per-slice dst prefixes and the dst half is dead -> edge_src overlays it.
    unsigned int* hist = (unsigned int*)p;
    int* edge_src = (int*)(hist + (size_t)NB * NW8);
    size_t dstHalf = (size_t)NB * NW8 * 4;
    size_t edgeBytes = (size_t)E * 4;
    p += align256((size_t)NB * NW8 * 4 + (edgeBytes > dstHalf ? edgeBytes : dstHalf));
    int* offsets = (int*)p;      p += align256((size_t)(N + 1) * sizeof(int));
    int* partial = (int*)p;      p += align256(64 * sizeof(int));
    int* histdone = (int*)p;     p += align256(sizeof(int));
    float* norm_out = (float*)p; p += align256((size_t)N * sizeof(float));
    float* norm_in  = (float*)p; p += align256((size_t)N * sizeof(float));
    float* beff  = (float*)p;    p += align256(128 * sizeof(float));
    unsigned short* xh  = (unsigned short*)p; p += align256((size_t)N * D * 2);
    unsigned short* yh  = (unsigned short*)p; p += align256((size_t)N * D * 2);
    unsigned int* xs8   = (unsigned int*)p;   p += align256((size_t)N * D);
    unsigned short* Wt  = (unsigned short*)p; p += align256(256 * 128 * 2);

    hipMemsetAsync(histdone, 0, sizeof(int), stream);
    k_front<<<2 * NB + 129 + nbh + nC4, 256, 0, stream>>>(
        src, dst, hist, E, NW8, nbh, N,
        x, xh, xs8, total4,
        Wconv, Waggr, bconv, baggr, Wt, beff,
        partial, histdone, norm_out, norm_in, offsets);
    k_scatter<<<NB * RS, 1024, 0, stream>>>(src, dst, offsets, hist, edge_src, E, NW8, RS);
    k_aggr<<<(N + 3) / 4, 256, 0, stream>>>(xs8, edge_src, offsets, norm_out, norm_in, yh, N);
    k_gemm<<<(N + 63) / 64, 256, 0, stream>>>(yh, xh, Wt, beff, out, N);
}

// Round 12
// 180.342 us; speedup vs baseline: 1.0605x; 1.0605x over previous
//
#include <hip/hip_runtime.h>

#define D 128
#define NB 64               // histogram/scatter slices
#define HWORDS 12544        // full-N byte-packed hist words (50176 B LDS, single pass)
#define HRANGE (HWORDS * 4)
#define RBITS 14            // scatter z-split: 16384 bins per range
#define RSIZE (1 << RBITS)
#define RWORDS8 (RSIZE / 4) // 4096 byte-packed words = 16 KB LDS
#define WT_STRIDE 136

typedef short short8 __attribute__((ext_vector_type(8)));
typedef float f32x4 __attribute__((ext_vector_type(4)));
typedef float f32x2 __attribute__((ext_vector_type(2)));

static __device__ __forceinline__ unsigned short f2bf(float f) {
    unsigned int u = __float_as_uint(f);
    unsigned int r = (u + 0x7FFFu + ((u >> 16) & 1u)) >> 16;
    return (unsigned short)r;
}
static __device__ __forceinline__ unsigned int pk2bf(float lo, float hi) {
    return (unsigned int)f2bf(lo) | ((unsigned int)f2bf(hi) << 16);
}

// Counts byte-packed (4 nodes/word): per-slice count and cumulative per-node
// prefix are both bounded by total degree ~ Poisson(16) tail < 64 << 255.

// ---------------- S1: zone A = per-(type,slice) SINGLE-PASS full-N byte-packed LDS
//                  histograms (int4 edge reads); zone C = weight fold + partial zero.
//                  (x conversions live in k_scanconv to overlap the 49-block scan.) ----------------
__global__ __launch_bounds__(1024) void k_stage1(
    const int* __restrict__ src, const int* __restrict__ dst,
    unsigned int* __restrict__ hist, int E, int NW8, int nHistA, int RS_A,
    const float* __restrict__ Wc, const float* __restrict__ Wa,
    const float* __restrict__ bc, const float* __restrict__ ba,
    unsigned short* __restrict__ Wt, float* __restrict__ beff,
    int* __restrict__ partial) {
    __shared__ unsigned int h[HWORDS];
    int t = threadIdx.x;
    int bx = blockIdx.x;

    if (bx < nHistA) {
        int g = bx / RS_A;
        int z = bx % RS_A;                // z==0 single pass while N <= 50176
        int type = g / NB;
        int b = g % NB;
        const int* __restrict__ ids = type ? dst : src;
        for (int i = t; i < HWORDS; i += 1024) h[i] = 0;
        __syncthreads();
        int slice = (E + NB - 1) / NB;
        int beg = b * slice;
        int end = beg + slice; if (end > E) end = E;
        int zb = z * HRANGE;
#define HPROC(vv) { unsigned int lv = (unsigned int)((vv) - zb); \
                    if (lv < (unsigned int)HRANGE) atomicAdd(&h[lv >> 2], 1u << ((lv & 3) * 8)); }
        int a0 = (beg + 3) & ~3; if (a0 > end) a0 = end;
        int a1 = a0 + ((end - a0) & ~3);
        for (int e = beg + t; e < a0; e += 1024) HPROC(ids[e]);
        int nv = (a1 - a0) >> 2;
        const int4* idv = (const int4*)(ids + a0);
        for (int i = t; i < nv; i += 1024) {
            int4 v4 = idv[i];
            HPROC(v4.x); HPROC(v4.y); HPROC(v4.z); HPROC(v4.w);
        }
        for (int e = a1 + t; e < end; e += 1024) HPROC(ids[e]);
#undef HPROC
        __syncthreads();
        unsigned int* outp = hist + (size_t)(type * NB + b) * NW8;
        int wbeg = z * HWORDS;
        int wend = wbeg + HWORDS; if (wend > NW8) wend = NW8;
        for (int i = wbeg + t; i < wend; i += 1024) outp[i] = h[i - wbeg];
    } else {
        // ---- zone C: Wt[j*256+k] = k<128 ? (Wc@Wa_top)[k][j] : Wa[k][j]; beff;
        //      plus zero the lookback partials (<= 64) ----
        int cidx = bx - nHistA;
        if (cidx < 32) {
            int o = cidx * 1024 + t;
            int k = o >> 7;
            int j = o & 127;
            float acc;
            if (k < 128) {
                acc = 0.f;
                for (int l = 0; l < 128; l++) acc += Wc[k * 128 + l] * Wa[l * 128 + j];
            } else {
                acc = Wa[k * 128 + j];
            }
            Wt[(size_t)j * 256 + k] = f2bf(acc);
        } else {
            if (t < 128) {
                float acc = ba[t];
                for (int k = 0; k < 128; k++) acc += bc[k] * Wa[k * 128 + t];
                beff[t] = acc;
            } else if (t < 192) {
                partial[t - 128] = 0;
            }
        }
    }
}

// ---------------- S2 fused: blocks < nbh run the proven hredscan (hist reduce ->
//                  norms + prefix rewrite + decoupled-lookback scan -> offsets);
//                  remaining blocks run x->bf16 + x->fp8 conversions, filling the
//                  ~80% of the device the 49 scan blocks leave idle. ----------------
__global__ __launch_bounds__(256) void k_scanconv(
    unsigned int* __restrict__ hist,
    float* __restrict__ norm_out, float* __restrict__ norm_in,
    int* __restrict__ partial, int* __restrict__ offsets,
    int N, int NW8, int nbh,
    const float* __restrict__ x, unsigned short* __restrict__ xh,
    unsigned int* __restrict__ xs8, long long total4) {
    __shared__ int red[256];
    int t = threadIdx.x;
    int bx = blockIdx.x;
    if (bx < nbh) {
        int w = bx * 256 + t;
        unsigned int p[4] = {0, 0, 0, 0};
        if (w < NW8) {
            unsigned int dout[4] = {0, 0, 0, 0};
            for (int b = 0; b < NB; b++) {
                unsigned int v = hist[(size_t)b * NW8 + w];
                dout[0] += v & 0xffu;         dout[1] += (v >> 8) & 0xffu;
                dout[2] += (v >> 16) & 0xffu; dout[3] += v >> 24;
            }
            for (int b = 0; b < NB; b++) {
                unsigned int v = hist[(size_t)(NB + b) * NW8 + w];
                // thread-exclusive word: no race
                hist[(size_t)b * NW8 + w] = p[0] | (p[1] << 8) | (p[2] << 16) | (p[3] << 24);
                p[0] += v & 0xffu;         p[1] += (v >> 8) & 0xffu;
                p[2] += (v >> 16) & 0xffu; p[3] += v >> 24;
            }
            int n0 = 4 * w;
#pragma unroll
            for (int j = 0; j < 4; j++) {
                int n = n0 + j;
                if (n < N) {
                    norm_out[n] = rsqrtf((float)(dout[j] > 1 ? dout[j] : 1));
                    norm_in[n]  = rsqrtf((float)(p[j] > 1 ? p[j] : 1));
                } else {
                    p[j] = 0;
                }
            }
        }
        int s = (int)(p[0] + p[1] + p[2] + p[3]);
        red[t] = s;
        __syncthreads();
        for (int off = 1; off < 256; off <<= 1) {
            int a = (t >= off) ? red[t - off] : 0;
            __syncthreads();
            red[t] += a;
            __syncthreads();
        }
        int incl = red[t];
        if (t == 0) atomicExch(&partial[bx], red[255] + 1);  // publish (pre-zeroed)
        int pv = 0;
        if (t < bx) {                                        // lookback spin (nbh <= 64)
            int v;
            do { v = atomicAdd(&partial[t], 0); } while (v == 0);
            pv = v - 1;
        }
        __syncthreads();
        red[t] = pv;
        __syncthreads();
        for (int off = 128; off > 0; off >>= 1) {
            if (t < off) red[t] += red[t + off];
            __syncthreads();
        }
        int base = red[0];
        int excl = incl - s + base;
        int n0 = bx * 1024 + t * 4;
        if (n0 < N)     offsets[n0]     = excl;
        if (n0 + 1 < N) offsets[n0 + 1] = excl + (int)p[0];
        if (n0 + 2 < N) offsets[n0 + 2] = excl + (int)(p[0] + p[1]);
        if (n0 + 3 < N) offsets[n0 + 3] = excl + (int)(p[0] + p[1] + p[2]);
        if (bx == nbh - 1 && t == 255) offsets[N] = base + incl;
    } else {
        // ---- conversions: x -> bf16 (GEMM operand) and x -> fp8 e4m3 (gather).
        // fp8 quantized from UNSCALED x (R1: folding norm in doubles absmax).
        long long i = (long long)(bx - nbh) * 256 + t;
        if (i < total4) {
            float4 v = *(const float4*)&x[i * 4];
            ushort4 o;
            o.x = f2bf(v.x); o.y = f2bf(v.y); o.z = f2bf(v.z); o.w = f2bf(v.w);
            *(ushort4*)&xh[i * 4] = o;
            unsigned int p8 = __builtin_amdgcn_cvt_pk_fp8_f32(v.x, v.y, 0u, false);
            p8 = __builtin_amdgcn_cvt_pk_fp8_f32(v.z, v.w, p8, true);
            xs8[i] = p8;
        }
    }
}

// ---------------- S3: counting-sort scatter — no global atomics; XCD-grouped z;
//                  int4 dst reads (src gathered only for in-range edges) ----------------
__global__ __launch_bounds__(1024) void k_scatter(const int* __restrict__ src,
                                                  const int* __restrict__ dst,
                                                  const int* __restrict__ offsets,
                                                  const unsigned int* __restrict__ prefix,
                                                  int* __restrict__ edge_src,
                                                  int E, int NW8, int RS) {
    __shared__ unsigned int h[RWORDS8];
    int t = threadIdx.x;
    int bx = blockIdx.x;
    int low3 = bx & 7;                    // bx = (b&7) + 8*(z + RS*(b>>3))
    int rest = bx >> 3;
    int z = rest % RS;
    int b = (rest / RS) * 8 + low3;
    for (int i = t; i < RWORDS8; i += 1024) h[i] = 0;
    __syncthreads();
    int slice = (E + NB - 1) / NB;
    int beg = b * slice;
    int end = beg + slice; if (end > E) end = E;
    const unsigned int* __restrict__ prow = prefix + (size_t)b * NW8;
#define SPROC(dd, ee) { int d = (dd); \
        if ((d >> RBITS) == z) { \
            int lv = d & (RSIZE - 1); \
            int sh = (lv & 3) * 8; \
            unsigned int old = atomicAdd(&h[lv >> 2], 1u << sh); \
            int rank = (int)((old >> sh) & 0xffu); \
            int base = offsets[d] + (int)((prow[d >> 2] >> sh) & 0xffu); \
            edge_src[base + rank] = src[ee]; } }
    int a0 = (beg + 3) & ~3; if (a0 > end) a0 = end;
    int a1 = a0 + ((end - a0) & ~3);
    for (int e = beg + t; e < a0; e += 1024) SPROC(dst[e], e);
    int nv = (a1 - a0) >> 2;
    const int4* dv = (const int4*)(dst + a0);
    for (int i = t; i < nv; i += 1024) {
        int4 d4 = dv[i];
        int e = a0 + i * 4;
        SPROC(d4.x, e); SPROC(d4.y, e + 1); SPROC(d4.z, e + 2); SPROC(d4.w, e + 3);
    }
    for (int e = a1 + t; e < end; e += 1024) SPROC(dst[e], e);
#undef SPROC
}

// ---------------- S4: CSR aggregation over fp8 rows: one node per wave (R5 lesson:
//                  the gather loop is latency-bound — never serialize nodes per wave) ----------------
__global__ __launch_bounds__(256) void k_aggr(const unsigned int* __restrict__ xs8,
                                              const int* __restrict__ edge_src,
                                              const int* __restrict__ offsets,
                                              const float* __restrict__ norm_out,
                                              const float* __restrict__ norm_in,
                                              unsigned short* __restrict__ yh, int N) {
    int node = blockIdx.x * 4 + (threadIdx.x >> 6);
    int lane = threadIdx.x & 63;
    if (node >= N) return;
    int g = lane >> 5;       // group 0/1
    int li = lane & 31;      // lane-in-group: elems li*4 .. li*4+3
    int beg = offsets[node];
    int end = offsets[node + 1];
    float nd = norm_in[node];
    float acc[4] = {0.f, 0.f, 0.f, 0.f};

    for (int jb = beg; jb < end; jb += 64) {
        int cnt = end - jb; if (cnt > 64) cnt = 64;
        int eidx = 0; float nsv = 0.f;
        if (lane < cnt) {
            eidx = edge_src[jb + lane];     // one coalesced batch load
            nsv  = norm_out[eidx];          // 64 norm gathers in flight
        }
        int k = 0;
        for (; k + 16 <= cnt; k += 16) {
#pragma unroll
            for (int u = 0; u < 16; u += 2) {   // 16 rows in flight across both groups
                int kg = k + u + g;
                int s = __shfl(eidx, kg);
                float ns = __shfl(nsv, kg);
                unsigned int v = xs8[(size_t)s * 32 + li];   // 32 words per 128-elem row
                f32x2 lo = __builtin_amdgcn_cvt_pk_f32_fp8(v, false);
                f32x2 hi = __builtin_amdgcn_cvt_pk_f32_fp8(v, true);
                acc[0] += lo[0] * ns;
                acc[1] += lo[1] * ns;
                acc[2] += hi[0] * ns;
                acc[3] += hi[1] * ns;
            }
        }
        for (; k < cnt; k += 2) {
            int kg = k + g;
            if (kg < cnt) {
                int s = __shfl(eidx, kg);
                float ns = __shfl(nsv, kg);
                unsigned int v = xs8[(size_t)s * 32 + li];
                f32x2 lo = __builtin_amdgcn_cvt_pk_f32_fp8(v, false);
                f32x2 hi = __builtin_amdgcn_cvt_pk_f32_fp8(v, true);
                acc[0] += lo[0] * ns;
                acc[1] += lo[1] * ns;
                acc[2] += hi[0] * ns;
                acc[3] += hi[1] * ns;
            }
        }
    }

    // combine the 2 groups (butterfly over lane bit 5)
#pragma unroll
    for (int i = 0; i < 4; i++) acc[i] += __shfl_xor(acc[i], 32);

    if (g == 0) {
        uint2 o;
        o.x = pk2bf(acc[0] * nd, acc[1] * nd);
        o.y = pk2bf(acc[2] * nd, acc[3] * nd);
        *(uint2*)&yh[(size_t)node * D + li * 4] = o;
    }
}

// ---------------- S5: MFMA GEMM: out = [yh | xh] @ W + beff ----------------
__global__ __launch_bounds__(256) void k_gemm(const unsigned short* __restrict__ yh,
                                              const unsigned short* __restrict__ xh,
                                              const unsigned short* __restrict__ Wt,
                                              const float* __restrict__ beff,
                                              float* __restrict__ out, int N) {
    __shared__ unsigned short Bs[128 * WT_STRIDE];

    int t = threadIdx.x;
    int w = t >> 6;
    int lane = t & 63;
    int m = lane & 15;
    int q = lane >> 4;
    int row0 = blockIdx.x * 64;
    int arow = row0 + w * 16 + m;
    bool arow_ok = arow < N;

    f32x4 acc[8];
#pragma unroll
    for (int ct = 0; ct < 8; ct++) acc[ct] = (f32x4){0.f, 0.f, 0.f, 0.f};

    for (int kh = 0; kh < 2; kh++) {
#pragma unroll
        for (int i = 0; i < 8; i++) {
            int idx = t + i * 256;
            int rr = idx >> 4;
            int cc = (idx & 15) * 8;
            *(short8*)&Bs[rr * WT_STRIDE + cc] =
                *(const short8*)&Wt[(size_t)rr * 256 + kh * 128 + cc];
        }
        __syncthreads();

        const unsigned short* Abase = (kh == 0) ? yh : xh;
        const unsigned short* arowp = Abase + (size_t)arow * D;

#pragma unroll
        for (int kk = 0; kk < 4; kk++) {
            short8 a = (short8){0,0,0,0,0,0,0,0};
            if (arow_ok) a = *(const short8*)&arowp[kk * 32 + q * 8];
#pragma unroll
            for (int ct = 0; ct < 8; ct++) {
                short8 b = *(const short8*)&Bs[(ct * 16 + m) * WT_STRIDE + kk * 32 + q * 8];
                acc[ct] = __builtin_amdgcn_mfma_f32_16x16x32_bf16(a, b, acc[ct], 0, 0, 0);
            }
        }
        __syncthreads();
    }

#pragma unroll
    for (int ct = 0; ct < 8; ct++) {
        int col = ct * 16 + m;
        float bv = beff[col];
#pragma unroll
        for (int j = 0; j < 4; j++) {
            int r = row0 + w * 16 + q * 4 + j;
            if (r < N) out[(size_t)r * D + col] = acc[ct][j] + bv;
        }
    }
}

static size_t align256(size_t v) { return (v + 255) & ~(size_t)255; }

extern "C" void kernel_launch(void* const* d_in, const int* in_sizes, int n_in,
                              void* d_out, int out_size, void* d_ws, size_t ws_size,
                              hipStream_t stream) {
    const float* x     = (const float*)d_in[0];
    const int*   src   = (const int*)d_in[1];
    const int*   dst   = (const int*)d_in[2];
    const float* Wconv = (const float*)d_in[3];
    const float* bconv = (const float*)d_in[4];
    const float* Waggr = (const float*)d_in[5];
    const float* baggr = (const float*)d_in[6];
    float* out = (float*)d_out;

    int N = in_sizes[0] / D;
    int E = in_sizes[1];
    int NW8 = (N + 3) / 4;                  // byte-packed words per histogram row
    int RS_A = (N + HRANGE - 1) / HRANGE;   // zone-A passes (1 at N=50000)
    int RS = (N + RSIZE - 1) / RSIZE;       // scatter z-splits (4 at N=50000)
    int nbh = (NW8 + 255) / 256;            // scan blocks (1024 nodes each, <= 64)
    int nHistA = NB * 2 * RS_A;
    long long total4 = (long long)N * D / 4;
    int nC4 = (int)((total4 + 255) / 256);  // conversion blocks (256 thr, 1 float4/thr)

    char* p = (char*)d_ws;
    // hist: [src half: NB rows][dst half: NB rows]; after k_scanconv the src half
    // holds per-slice dst prefixes and the dst half is dead -> edge_src overlays it.
    unsigned int* hist = (unsigned int*)p;
    int* edge_src = (int*)(hist + (size_t)NB * NW8);
    size_t dstHalf = (size_t)NB * NW8 * 4;
    size_t edgeBytes = (size_t)E * 4;
    p += align256((size_t)NB * NW8 * 4 + (edgeBytes > dstHalf ? edgeBytes : dstHalf));
    int* offsets = (int*)p;      p += align256((size_t)(N + 1) * sizeof(int));
    int* partial = (int*)p;      p += align256(64 * sizeof(int));
    float* norm_out = (float*)p; p += align256((size_t)N * sizeof(float));
    float* norm_in  = (float*)p; p += align256((size_t)N * sizeof(float));
    float* beff  = (float*)p;    p += align256(128 * sizeof(float));
    unsigned short* xh  = (unsigned short*)p; p += align256((size_t)N * D * 2);
    unsigned short* yh  = (unsigned short*)p; p += align256((size_t)N * D * 2);
    unsigned int* xs8   = (unsigned int*)p;   p += align256((size_t)N * D);
    unsigned short* Wt  = (unsigned short*)p; p += align256(256 * 128 * 2);

    k_stage1<<<nHistA + 33, 1024, 0, stream>>>(
        src, dst, hist, E, NW8, nHistA, RS_A,
        Wconv, Waggr, bconv, baggr, Wt, beff, partial);
    k_scanconv<<<nbh + nC4, 256, 0, stream>>>(
        hist, norm_out, norm_in, partial, offsets, N, NW8, nbh,
        x, xh, xs8, total4);
    k_scatter<<<NB * RS, 1024, 0, stream>>>(src, dst, offsets, hist, edge_src, E, NW8, RS);
    k_aggr<<<(N + 3) / 4, 256, 0, stream>>>(xs8, edge_src, offsets, norm_out, norm_in, yh, N);
    k_gemm<<<(N + 63) / 64, 256, 0, stream>>>(yh, xh, Wt, beff, out, N);
}